// Round 14
// baseline (32472.586 us; speedup 1.0000x reference)
//
#include <hip/hip_runtime.h>
#include <hip/hip_fp16.h>
#include <math.h>

#define R_DIM 4096
#define I_DIM 64
#define O_DIM 64
#define T_DIM 8192
#define NBLK  256
#define NTHR  512
#define RPB   16          // reservoir rows per block

// raw barrier: waits LDS ops only -- deliberately NO vmcnt drain
#define LBAR() asm volatile("s_waitcnt lgkmcnt(0)\n\ts_barrier" ::: "memory")

// fast tanh: exact at saturation, ~1e-6 rel err in between
__device__ __forceinline__ float ftanh(float x) {
    float e = __expf(2.f * x);
    return 1.f - __fdividef(2.f, e + 1.f);
}

// d_ws layout:
//   [0 .. 32KB)   : pair double buffer  2 x 4096 x u32 {tag16, f16 val}
//   [64KB .. )    : Shist[T][R] f32 (HIST mode only, 128 MB)

__global__ __launch_bounds__(NTHR, 2) void esn_persist(
    const float* __restrict__ X, const float* __restrict__ Wres,
    const float* __restrict__ Win, const float* __restrict__ Wout,
    float* __restrict__ out, unsigned* __restrict__ pairs,
    float* __restrict__ Shist, int use_hist)
{
    __shared__ float wred[2][8][RPB];   // per-wave row partials, parity dbuf
    __shared__ float wred_x[RPB];       // Win @ x_t per row (wave0-owned)
    __shared__ float snew[RPB];         // published state (fallback readout)

    const int tid  = threadIdx.x;
    const int b    = blockIdx.x;
    const int lane = tid & 63;
    const int w    = tid >> 6;        // wave 0..7
    const int R0   = b * RPB;

    // ---- one-time: K-split weights -- wave w, lane l owns cols w*512 + k*64 + l,
    //      all 16 rows: 128 floats in registers, pinned via asm ----
    float wr[RPB][8];
#pragma unroll
    for (int r = 0; r < RPB; ++r) {
        const float* rowp = Wres + (size_t)(R0 + r) * R_DIM + w * 512 + lane;
#pragma unroll
        for (int k = 0; k < 8; ++k)
            wr[r][k] = rowp[k * 64];
    }
#pragma unroll
    for (int r = 0; r < RPB; ++r)
        asm volatile("" : "+v"(wr[r][0]), "+v"(wr[r][1]), "+v"(wr[r][2]), "+v"(wr[r][3]),
                          "+v"(wr[r][4]), "+v"(wr[r][5]), "+v"(wr[r][6]), "+v"(wr[r][7]));

    // wave0: Win slice -- lane l covers row l>>2, cols (l&3)*16 .. +16
    float winv[16];
#pragma unroll
    for (int j = 0; j < 16; ++j) winv[j] = 0.f;
    float4 xv4[4] = {};
    if (w == 0) {
        const float* wp = Win + (size_t)(R0 + (lane >> 2)) * I_DIM + (lane & 3) * 16;
#pragma unroll
        for (int j = 0; j < 16; ++j) winv[j] = wp[j];
        const float4* xp = (const float4*)(X + (lane & 3) * 16);
#pragma unroll
        for (int j = 0; j < 4; ++j) xv4[j] = xp[j];
    }
    float4 wo4[4] = {};
    if (!use_hist && w == 1) {   // fallback readout wave: o = lane
#pragma unroll
        for (int j = 0; j < 4; ++j)
            wo4[j] = *(const float4*)(Wout + (size_t)lane * (I_DIM + R_DIM) + I_DIM + R0 + j * 4);
    }

    for (int t = 0; t < T_DIM; ++t) {
        // ======== wave0: Win @ x_t from prefetched regs; then issue x_{t+1} loads ========
        if (w == 0) {
            const float* xs = (const float*)xv4;
            float acc = 0.f;
#pragma unroll
            for (int j = 0; j < 16; ++j) acc += winv[j] * xs[j];
            acc += __shfl_xor(acc, 1);
            acc += __shfl_xor(acc, 2);
            if ((lane & 3) == 0) wred_x[lane >> 2] = acc;
            if (t + 1 < T_DIM) {
                const float4* xp = (const float4*)(X + (size_t)(t + 1) * I_DIM + (lane & 3) * 16);
#pragma unroll
                for (int j = 0; j < 4; ++j) xv4[j] = xp[j];
            }
        }

        // ======== poll own 512-word chunk: dead-zone probe then hot sweep ========
        float acc[RPB];
#pragma unroll
        for (int r = 0; r < RPB; ++r) acc[r] = 0.f;
        {
            unsigned* rbuf = pairs + ((t + 1) & 1) * R_DIM;  // S_{t-1}, tag t
            const unsigned tagmin = (unsigned)t;
            const int base = w * 512 + lane;
            __builtin_amdgcn_s_setprio(0);   // spin phase: deprioritize
            // ---- dead zone: probe ONLY k=0 (1 line/wave/round), minimal backoff ----
            unsigned p0;
            while (1) {
                p0 = __hip_atomic_load(&rbuf[base], __ATOMIC_RELAXED, __HIP_MEMORY_SCOPE_AGENT);
                if ((p0 >> 16) >= tagmin) break;
                __builtin_amdgcn_s_sleep(1);   // sleep(4) caused 110ms outlier resonance (R13)
            }
            {
                const float s = __half2float(__ushort_as_half((unsigned short)(p0 & 0xFFFFu)));
#pragma unroll
                for (int r = 0; r < RPB; ++r) acc[r] += wr[r][0] * s;
            }
            // ---- hot phase: masked full sweeps, FMA-on-arrival, no sleep ----
            unsigned got = 1u;
            while (got != 0xFFu) {
#pragma unroll
                for (int k = 1; k < 8; ++k) {
                    if (!(got & (1u << k))) {
                        unsigned p = __hip_atomic_load(&rbuf[base + k * 64],
                                      __ATOMIC_RELAXED, __HIP_MEMORY_SCOPE_AGENT);
                        if ((p >> 16) >= tagmin) {
                            got |= 1u << k;
                            const float s = __half2float(__ushort_as_half((unsigned short)(p & 0xFFFFu)));
#pragma unroll
                            for (int r = 0; r < RPB; ++r) acc[r] += wr[r][k] * s;
                        }
                    }
                }
            }
            __builtin_amdgcn_s_setprio(1);   // data ready: critical path
        }

        // ======== specialized butterfly: 16 accs over 64 lanes (~64 ops) ========
#pragma unroll
        for (int j = 0; j < 8; ++j) {
            const bool bb = lane & 1;
            float send = bb ? acc[j] : acc[j + 8];
            float keep = bb ? acc[j + 8] : acc[j];
            acc[j] = keep + __shfl_xor(send, 1);
        }
#pragma unroll
        for (int j = 0; j < 4; ++j) {
            const bool bb = lane & 2;
            float send = bb ? acc[j] : acc[j + 4];
            float keep = bb ? acc[j + 4] : acc[j];
            acc[j] = keep + __shfl_xor(send, 2);
        }
#pragma unroll
        for (int j = 0; j < 2; ++j) {
            const bool bb = lane & 4;
            float send = bb ? acc[j] : acc[j + 2];
            float keep = bb ? acc[j + 2] : acc[j];
            acc[j] = keep + __shfl_xor(send, 4);
        }
        {
            const bool bb = lane & 8;
            float send = bb ? acc[0] : acc[1];
            float keep = bb ? acc[1] : acc[0];
            acc[0] = keep + __shfl_xor(send, 8);
        }
        acc[0] += __shfl_xor(acc[0], 16);
        acc[0] += __shfl_xor(acc[0], 32);
        const int rl = ((lane & 1) << 3) | ((lane & 2) << 1) | ((lane & 4) >> 1) | ((lane & 8) >> 3);
        if (lane < 16) wred[t & 1][w][rl] = acc[0];

        LBAR();   // the ONLY per-step barrier: all wave partials + wred_x visible

        // ======== TAIL: wave0 sums partials, tanh, publishes 1 coalesced line ========
        if (w == 0) {
            asm volatile("s_waitcnt vmcnt(0)" ::: "memory");
            if (lane < RPB) {
                float pre = wred_x[lane];
#pragma unroll
                for (int wv = 0; wv < 8; ++wv) pre += wred[t & 1][wv][lane];
                float s = ftanh(pre);
                unsigned pack = ((unsigned)(t + 1) << 16)
                              | (unsigned)__half_as_ushort(__float2half(s));
                __hip_atomic_store(&pairs[(t & 1) * R_DIM + R0 + lane], pack,
                                   __ATOMIC_RELAXED, __HIP_MEMORY_SCOPE_AGENT);
                if (use_hist) Shist[(size_t)t * R_DIM + R0 + lane] = s;
                snew[lane] = s;
            }
        }

        if (!use_hist) {
            LBAR();   // snew visible to wave1
            if (w == 1) {
                float y = 0.f;
#pragma unroll
                for (int j = 0; j < 16; ++j)
                    y += ((const float*)wo4)[j] * snew[j];
                __hip_atomic_fetch_add(&out[(size_t)t * O_DIM + lane], y,
                                       __ATOMIC_RELAXED, __HIP_MEMORY_SCOPE_AGENT);
            }
        }
    }
}

// y_x[t,o] = Wout[o, :64] . x_t  -- plain writes, runs first
__global__ void esn_xpart(const float* __restrict__ X, const float* __restrict__ Wout,
                          float* __restrict__ out)
{
    const int idx = blockIdx.x * blockDim.x + threadIdx.x;  // t*64 + o
    const int t = idx >> 6, o = idx & 63;
    const float4* xr = (const float4*)(X + (size_t)t * I_DIM);
    const float4* wr = (const float4*)(Wout + (size_t)o * (I_DIM + R_DIM));
    float y = 0.f;
#pragma unroll
    for (int j = 0; j < 16; ++j) {
        float4 a = xr[j], b = wr[j];
        y += a.x * b.x + a.y * b.y + a.z * b.z + a.w * b.w;
    }
    out[idx] = y;
}

// HIST mode: out[t,o] += Wout[o, 64:] . Shist[t]  -- massively parallel, no atomics
__global__ void esn_readout(const float* __restrict__ Shist, const float* __restrict__ Wout,
                            float* __restrict__ out)
{
    const int idx = blockIdx.x * blockDim.x + threadIdx.x;  // t*64 + o
    const int t = idx >> 6, o = idx & 63;
    const float4* s4 = (const float4*)(Shist + (size_t)t * R_DIM);
    const float4* w4 = (const float4*)(Wout + (size_t)o * (I_DIM + R_DIM) + I_DIM);
    float y = 0.f;
#pragma unroll 4
    for (int j = 0; j < R_DIM / 4; ++j) {
        float4 a = s4[j], b = w4[j];
        y += a.x * b.x + a.y * b.y + a.z * b.z + a.w * b.w;
    }
    out[idx] += y;
}

extern "C" void kernel_launch(void* const* d_in, const int* in_sizes, int n_in,
                              void* d_out, int out_size, void* d_ws, size_t ws_size,
                              hipStream_t stream)
{
    (void)in_sizes; (void)n_in; (void)out_size;
    const float* X    = (const float*)d_in[0];
    const float* Win  = (const float*)d_in[1];
    const float* Wres = (const float*)d_in[2];
    const float* Wout = (const float*)d_in[3];
    float* out = (float*)d_out;

    unsigned* pairs = (unsigned*)d_ws;
    float* Shist = (float*)((char*)d_ws + 65536);
    const size_t hist_bytes = (size_t)T_DIM * R_DIM * sizeof(float);
    const int use_hist = (ws_size >= 65536 + hist_bytes) ? 1 : 0;

    // reset pair tags every call (stale tags would break polling)
    hipMemsetAsync(d_ws, 0, 2 * R_DIM * sizeof(unsigned), stream);

    // x-part of readout initializes all of d_out
    esn_xpart<<<(T_DIM * O_DIM) / 256, 256, 0, stream>>>(X, Wout, out);

    void* args[] = { (void*)&X, (void*)&Wres, (void*)&Win, (void*)&Wout,
                     (void*)&out, (void*)&pairs, (void*)&Shist, (void*)&use_hist };
    hipLaunchCooperativeKernel((const void*)esn_persist, dim3(NBLK), dim3(NTHR),
                               args, 0, stream);

    if (use_hist)
        esn_readout<<<(T_DIM * O_DIM) / 256, 256, 0, stream>>>(Shist, Wout, out);
}